// Round 7
// baseline (123.469 us; speedup 1.0000x reference)
//
#include <hip/hip_runtime.h>

#define EPSILON_F 5.0f
#define FIXED_SCALE 4294967296.0  // 2^32: sum <= 5*262144*2^32 = 5.6e15 << 2^63

// Single fused kernel. Pass-1 body identical to R6 (8-row chunks, reduced
// shuffles, plain cached loads). Block partials are accumulated into one
// global int64 fixed-point accumulator: integer atomics are exactly
// commutative -> bit-identical result on every replay (deterministic),
// unlike float atomics. The last-arriving block (ticket counter) converts
// and writes the mean. Accumulator+counter are zeroed each call by a
// 16-byte hipMemsetAsync node (d_ws is poisoned 0xAA by the harness).
__global__ __launch_bounds__(256) void ncl_fused_kernel(
    const float* __restrict__ feat,     // [B, 256]
    const float* __restrict__ means,    // [C, 256]
    const int* __restrict__ labels,     // [B]
    unsigned long long* __restrict__ acc_fx,  // d_ws+0, zeroed
    unsigned* __restrict__ ticket,            // d_ws+8, zeroed
    float* __restrict__ out,
    int nchunks,                        // B / 8
    int B)
{
    const int lane = threadIdx.x & 63;
    const int wave = threadIdx.x >> 6;
    const int gwave = blockIdx.x * (blockDim.x >> 6) + wave;
    const int nwaves = gridDim.x * (blockDim.x >> 6);
    const int grp = lane >> 4;

    float acc = 0.0f;
    for (int c = gwave; c < nchunks; c += nwaves) {
        const size_t rb = (size_t)c * 8;
        const int4 lva = *reinterpret_cast<const int4*>(labels + rb);
        const int4 lvb = *reinterpret_cast<const int4*>(labels + rb + 4);

        const float* fp = feat + rb * 256 + lane * 4;
        const float4 f0 = *reinterpret_cast<const float4*>(fp);
        const float4 f1 = *reinterpret_cast<const float4*>(fp + 256);
        const float4 f2 = *reinterpret_cast<const float4*>(fp + 512);
        const float4 f3 = *reinterpret_cast<const float4*>(fp + 768);
        const float4 f4 = *reinterpret_cast<const float4*>(fp + 1024);
        const float4 f5 = *reinterpret_cast<const float4*>(fp + 1280);
        const float4 f6 = *reinterpret_cast<const float4*>(fp + 1536);
        const float4 f7 = *reinterpret_cast<const float4*>(fp + 1792);

        const float4 m0 = *reinterpret_cast<const float4*>(means + (size_t)lva.x * 256 + lane * 4);
        const float4 m1 = *reinterpret_cast<const float4*>(means + (size_t)lva.y * 256 + lane * 4);
        const float4 m2 = *reinterpret_cast<const float4*>(means + (size_t)lva.z * 256 + lane * 4);
        const float4 m3 = *reinterpret_cast<const float4*>(means + (size_t)lva.w * 256 + lane * 4);
        const float4 m4 = *reinterpret_cast<const float4*>(means + (size_t)lvb.x * 256 + lane * 4);
        const float4 m5 = *reinterpret_cast<const float4*>(means + (size_t)lvb.y * 256 + lane * 4);
        const float4 m6 = *reinterpret_cast<const float4*>(means + (size_t)lvb.z * 256 + lane * 4);
        const float4 m7 = *reinterpret_cast<const float4*>(means + (size_t)lvb.w * 256 + lane * 4);

        float d0, d1, d2, d3, d4, d5, d6, d7;
        { float x=f0.x-m0.x, y=f0.y-m0.y, z=f0.z-m0.z, w=f0.w-m0.w; d0 = x*x + y*y + z*z + w*w; }
        { float x=f1.x-m1.x, y=f1.y-m1.y, z=f1.z-m1.z, w=f1.w-m1.w; d1 = x*x + y*y + z*z + w*w; }
        { float x=f2.x-m2.x, y=f2.y-m2.y, z=f2.z-m2.z, w=f2.w-m2.w; d2 = x*x + y*y + z*z + w*w; }
        { float x=f3.x-m3.x, y=f3.y-m3.y, z=f3.z-m3.z, w=f3.w-m3.w; d3 = x*x + y*y + z*z + w*w; }
        { float x=f4.x-m4.x, y=f4.y-m4.y, z=f4.z-m4.z, w=f4.w-m4.w; d4 = x*x + y*y + z*z + w*w; }
        { float x=f5.x-m5.x, y=f5.y-m5.y, z=f5.z-m5.z, w=f5.w-m5.w; d5 = x*x + y*y + z*z + w*w; }
        { float x=f6.x-m6.x, y=f6.y-m6.y, z=f6.z-m6.z, w=f6.w-m6.w; d6 = x*x + y*y + z*z + w*w; }
        { float x=f7.x-m7.x, y=f7.y-m7.y, z=f7.z-m7.z, w=f7.w-m7.w; d7 = x*x + y*y + z*z + w*w; }

        d0 += __shfl_xor(d0, 32, 64); d1 += __shfl_xor(d1, 32, 64);
        d2 += __shfl_xor(d2, 32, 64); d3 += __shfl_xor(d3, 32, 64);
        d4 += __shfl_xor(d4, 32, 64); d5 += __shfl_xor(d5, 32, 64);
        d6 += __shfl_xor(d6, 32, 64); d7 += __shfl_xor(d7, 32, 64);
        d0 += __shfl_xor(d0, 16, 64); d1 += __shfl_xor(d1, 16, 64);
        d2 += __shfl_xor(d2, 16, 64); d3 += __shfl_xor(d3, 16, 64);
        d4 += __shfl_xor(d4, 16, 64); d5 += __shfl_xor(d5, 16, 64);
        d6 += __shfl_xor(d6, 16, 64); d7 += __shfl_xor(d7, 16, 64);

        float xa = (grp == 0) ? d0 : (grp == 1) ? d1 : (grp == 2) ? d2 : d3;
        float xb = (grp == 0) ? d4 : (grp == 1) ? d5 : (grp == 2) ? d6 : d7;

        xa += __shfl_xor(xa, 8, 64);  xb += __shfl_xor(xb, 8, 64);
        xa += __shfl_xor(xa, 4, 64);  xb += __shfl_xor(xb, 4, 64);
        xa += __shfl_xor(xa, 2, 64);  xb += __shfl_xor(xb, 2, 64);
        xa += __shfl_xor(xa, 1, 64);  xb += __shfl_xor(xb, 1, 64);

        acc += fmaxf(EPSILON_F - sqrtf(xa), 0.0f)
             + fmaxf(EPSILON_F - sqrtf(xb), 0.0f);
    }

    #pragma unroll
    for (int off = 32; off; off >>= 1) acc += __shfl_xor(acc, off, 64);

    __shared__ float wsum[4];
    if (lane == 0) wsum[wave] = acc * 0.0625f;
    __syncthreads();
    if (threadIdx.x == 0) {
        const float bp = wsum[0] + wsum[1] + wsum[2] + wsum[3];
        // non-negative block partial -> exact commutative integer accumulation
        const unsigned long long fx =
            (unsigned long long)(long long)rint((double)bp * FIXED_SCALE);
        atomicAdd(acc_fx, fx);
        __threadfence();  // release: my add visible before my ticket
        const unsigned old = atomicAdd(ticket, 1u);
        if (old == gridDim.x - 1) {
            // all adds complete; atomic read returns the coherent total
            const unsigned long long tot = atomicAdd(acc_fx, 0ULL);
            out[0] = (float)((double)tot / FIXED_SCALE / (double)B);
        }
    }
}

extern "C" void kernel_launch(void* const* d_in, const int* in_sizes, int n_in,
                              void* d_out, int out_size, void* d_ws, size_t ws_size,
                              hipStream_t stream)
{
    const float* feat   = (const float*)d_in[0];   // [B, 256] f32
    const float* means  = (const float*)d_in[1];   // [C, 256] f32
    const int*   labels = (const int*)d_in[2];     // [B] int
    float* out = (float*)d_out;

    const int B = in_sizes[0] / 256;
    const int NBLOCKS = 2048;

    unsigned long long* acc_fx = (unsigned long long*)d_ws;
    unsigned* ticket = (unsigned*)((char*)d_ws + 8);

    // zero accumulator + ticket (d_ws is poisoned 0xAA; captures as memset node)
    hipMemsetAsync(d_ws, 0, 16, stream);

    ncl_fused_kernel<<<NBLOCKS, 256, 0, stream>>>(
        feat, means, labels, acc_fx, ticket, out, B / 8, B);
}

// Round 8
// 48.398 us; speedup vs baseline: 2.5511x; 2.5511x over previous
//
#include <hip/hip_runtime.h>

#define EPSILON_F 5.0f

// R8 = exact revert to the R6 kernel (best measured: 48.4 us).
// R7 lesson: fusing the final reduce via same-cache-line atomics from 2048
// simultaneously-finishing blocks cost +75 us (serialized atomic burst at the
// device coherence point + perturbed regalloc, VGPR 48 -> serialized loads).
// Two-kernel structure is the right shape for this op.
//
// Pass 1: each wave processes chunks of 8 consecutive rows.
//  - two 16B broadcast int4 loads fetch 8 labels
//  - 8 feat float4 loads + 8 means float4 loads, plain cached loads
//    (R4 lesson: nontemporal loads cost ~10% here)
//  - reduced-shuffle reduction, 3 DS ops per row:
//      2 butterfly stages per row (off=32,16) -> partials indexed by lane&15,
//      4-way row select per 16-lane group (twice: rows 0-3 and rows 4-7),
//      4 shared stages (off=8,4,2,1) finishing two independent row-groups.
//    Each row's hinge is counted 16x across the wave -> final scale 1/16.
__global__ __launch_bounds__(256) void ncl_partial_kernel(
    const float* __restrict__ feat,     // [B, 256]
    const float* __restrict__ means,    // [C, 256]
    const int* __restrict__ labels,     // [B]
    float* __restrict__ partials,       // [gridDim.x]
    int nchunks)                        // B / 8
{
    const int lane = threadIdx.x & 63;
    const int wave = threadIdx.x >> 6;
    const int gwave = blockIdx.x * (blockDim.x >> 6) + wave;
    const int nwaves = gridDim.x * (blockDim.x >> 6);
    const int grp = lane >> 4;          // which row of each 4-row group this lane finishes

    float acc = 0.0f;
    for (int c = gwave; c < nchunks; c += nwaves) {
        const size_t rb = (size_t)c * 8;  // first row of this 8-row chunk
        const int4 lva = *reinterpret_cast<const int4*>(labels + rb);
        const int4 lvb = *reinterpret_cast<const int4*>(labels + rb + 4);

        const float* fp = feat + rb * 256 + lane * 4;
        const float4 f0 = *reinterpret_cast<const float4*>(fp);
        const float4 f1 = *reinterpret_cast<const float4*>(fp + 256);
        const float4 f2 = *reinterpret_cast<const float4*>(fp + 512);
        const float4 f3 = *reinterpret_cast<const float4*>(fp + 768);
        const float4 f4 = *reinterpret_cast<const float4*>(fp + 1024);
        const float4 f5 = *reinterpret_cast<const float4*>(fp + 1280);
        const float4 f6 = *reinterpret_cast<const float4*>(fp + 1536);
        const float4 f7 = *reinterpret_cast<const float4*>(fp + 1792);

        const float4 m0 = *reinterpret_cast<const float4*>(means + (size_t)lva.x * 256 + lane * 4);
        const float4 m1 = *reinterpret_cast<const float4*>(means + (size_t)lva.y * 256 + lane * 4);
        const float4 m2 = *reinterpret_cast<const float4*>(means + (size_t)lva.z * 256 + lane * 4);
        const float4 m3 = *reinterpret_cast<const float4*>(means + (size_t)lva.w * 256 + lane * 4);
        const float4 m4 = *reinterpret_cast<const float4*>(means + (size_t)lvb.x * 256 + lane * 4);
        const float4 m5 = *reinterpret_cast<const float4*>(means + (size_t)lvb.y * 256 + lane * 4);
        const float4 m6 = *reinterpret_cast<const float4*>(means + (size_t)lvb.z * 256 + lane * 4);
        const float4 m7 = *reinterpret_cast<const float4*>(means + (size_t)lvb.w * 256 + lane * 4);

        float d0, d1, d2, d3, d4, d5, d6, d7;
        { float x=f0.x-m0.x, y=f0.y-m0.y, z=f0.z-m0.z, w=f0.w-m0.w; d0 = x*x + y*y + z*z + w*w; }
        { float x=f1.x-m1.x, y=f1.y-m1.y, z=f1.z-m1.z, w=f1.w-m1.w; d1 = x*x + y*y + z*z + w*w; }
        { float x=f2.x-m2.x, y=f2.y-m2.y, z=f2.z-m2.z, w=f2.w-m2.w; d2 = x*x + y*y + z*z + w*w; }
        { float x=f3.x-m3.x, y=f3.y-m3.y, z=f3.z-m3.z, w=f3.w-m3.w; d3 = x*x + y*y + z*z + w*w; }
        { float x=f4.x-m4.x, y=f4.y-m4.y, z=f4.z-m4.z, w=f4.w-m4.w; d4 = x*x + y*y + z*z + w*w; }
        { float x=f5.x-m5.x, y=f5.y-m5.y, z=f5.z-m5.z, w=f5.w-m5.w; d5 = x*x + y*y + z*z + w*w; }
        { float x=f6.x-m6.x, y=f6.y-m6.y, z=f6.z-m6.z, w=f6.w-m6.w; d6 = x*x + y*y + z*z + w*w; }
        { float x=f7.x-m7.x, y=f7.y-m7.y, z=f7.z-m7.z, w=f7.w-m7.w; d7 = x*x + y*y + z*z + w*w; }

        // stage 1+2: after these, each lane's d_r = sum over lanes sharing (lane & 15)
        d0 += __shfl_xor(d0, 32, 64); d1 += __shfl_xor(d1, 32, 64);
        d2 += __shfl_xor(d2, 32, 64); d3 += __shfl_xor(d3, 32, 64);
        d4 += __shfl_xor(d4, 32, 64); d5 += __shfl_xor(d5, 32, 64);
        d6 += __shfl_xor(d6, 32, 64); d7 += __shfl_xor(d7, 32, 64);
        d0 += __shfl_xor(d0, 16, 64); d1 += __shfl_xor(d1, 16, 64);
        d2 += __shfl_xor(d2, 16, 64); d3 += __shfl_xor(d3, 16, 64);
        d4 += __shfl_xor(d4, 16, 64); d5 += __shfl_xor(d5, 16, 64);
        d6 += __shfl_xor(d6, 16, 64); d7 += __shfl_xor(d7, 16, 64);

        // 16-lane group g owns row g (first group of 4) and row g+4 (second)
        float xa = (grp == 0) ? d0 : (grp == 1) ? d1 : (grp == 2) ? d2 : d3;
        float xb = (grp == 0) ? d4 : (grp == 1) ? d5 : (grp == 2) ? d6 : d7;

        // shared stages: two independent chains finish 8 rows in 8 DS ops
        xa += __shfl_xor(xa, 8, 64);  xb += __shfl_xor(xb, 8, 64);
        xa += __shfl_xor(xa, 4, 64);  xb += __shfl_xor(xb, 4, 64);
        xa += __shfl_xor(xa, 2, 64);  xb += __shfl_xor(xb, 2, 64);
        xa += __shfl_xor(xa, 1, 64);  xb += __shfl_xor(xb, 1, 64);

        // each row counted 16x (corrected by 1/16 at the end)
        acc += fmaxf(EPSILON_F - sqrtf(xa), 0.0f)
             + fmaxf(EPSILON_F - sqrtf(xb), 0.0f);
    }

    // wave-reduce acc once per kernel (rows were counted 16x -> scale 1/16)
    #pragma unroll
    for (int off = 32; off; off >>= 1) acc += __shfl_xor(acc, off, 64);

    __shared__ float wsum[4];
    if (lane == 0) wsum[wave] = acc * 0.0625f;
    __syncthreads();
    if (threadIdx.x == 0)
        partials[blockIdx.x] = wsum[0] + wsum[1] + wsum[2] + wsum[3];
}

// Pass 2: deterministic reduce of block partials -> mean.
__global__ __launch_bounds__(256) void ncl_final_kernel(
    const float* __restrict__ partials, int n, float* __restrict__ out, float invB)
{
    float s = 0.0f;
    for (int i = threadIdx.x; i < n; i += 256) s += partials[i];
    #pragma unroll
    for (int off = 32; off; off >>= 1) s += __shfl_xor(s, off, 64);
    __shared__ float wsum[4];
    if ((threadIdx.x & 63) == 0) wsum[threadIdx.x >> 6] = s;
    __syncthreads();
    if (threadIdx.x == 0) out[0] = (wsum[0] + wsum[1] + wsum[2] + wsum[3]) * invB;
}

extern "C" void kernel_launch(void* const* d_in, const int* in_sizes, int n_in,
                              void* d_out, int out_size, void* d_ws, size_t ws_size,
                              hipStream_t stream)
{
    const float* feat   = (const float*)d_in[0];   // [B, 256] f32
    const float* means  = (const float*)d_in[1];   // [C, 256] f32
    const int*   labels = (const int*)d_in[2];     // [B] int
    float* out = (float*)d_out;

    const int B = in_sizes[0] / 256;
    const int NBLOCKS = 2048;
    float* partials = (float*)d_ws;  // 2048 floats = 8 KB scratch

    ncl_partial_kernel<<<NBLOCKS, 256, 0, stream>>>(feat, means, labels, partials, B / 8);
    ncl_final_kernel<<<1, 256, 0, stream>>>(partials, NBLOCKS, out, 1.0f / (float)B);
}